// Round 13
// baseline (15288.550 us; speedup 1.0000x reference)
//
#include <hip/hip_runtime.h>

// SparseGPT forward on MI355X. Round 13: bit-preserving perf round.
// - Attention rewritten: 4 q/block, 128 thr, LDS K-chunks, lane-parallel
//   XLA reduce tree (same add pairing), float4 PV. Per-output fp32 op order
//   identical to passing R11/R12.
// - GEMM: BN=64 variant for N=1024 GEMMs (full-GPU grids).
// - rmsnorm: lane-parallel reduce tree (same pairing).

typedef unsigned int u32;

#define TT 2048
#define DD 1024
#define HH 16
#define DMM 4096
#define VV 32000
#define AQ 4

// ---------------- embedding ----------------
__global__ __launch_bounds__(256) void embed32_k(const int* __restrict__ idx,
    const float* __restrict__ wte, const float* __restrict__ wpe, float* __restrict__ x){
  int t = blockIdx.x, tid = threadIdx.x;
  int tok = idx[t];
  #pragma unroll
  for (int i=0;i<4;i++){
    int e = tid*4 + i;
    x[(size_t)t*DD + e] = __fadd_rn(wte[(size_t)tok*DD + e], wpe[(size_t)t*DD + e]);
  }
}

// ------- rmsnorm, XLA replica; reduce tree lane-parallel (same pairing) -------
__global__ __launch_bounds__(64) void rms_xla_k(const float* __restrict__ x,
    const float* __restrict__ w, float* __restrict__ out){
  __shared__ float sq[1024];
  __shared__ float p5[512];
  __shared__ float fin[64];
  __shared__ float srt;
  int row = blockIdx.x, lane = threadIdx.x;
  const float* xr = x + (size_t)row*DD;
  for (int i=lane; i<1024; i+=64){ float v = xr[i]; sq[i] = __fmul_rn(v,v); }
  __syncthreads();
  for (int t=lane; t<512; t+=64)
    p5[t] = __fadd_rn(sq[2*t], sq[2*t+1]);
  __syncthreads();
  // 8 per-wave tree64's, lane-parallel, identical pairing to serial version
  #pragma unroll
  for (int off=32; off; off>>=1){
    for (int t=lane; t<8*off; t+=64){
      int wv = t/off, ii = t - wv*off;
      p5[64*wv+ii] = __fadd_rn(p5[64*wv+ii], p5[64*wv+ii+off]);
    }
    __syncthreads();
  }
  fin[lane] = (lane<8) ? p5[64*lane] : 0.0f;
  __syncthreads();
  #pragma unroll
  for (int off=32; off; off>>=1){
    if (lane<off) fin[lane] = __fadd_rn(fin[lane], fin[lane+off]);
    __syncthreads();
  }
  if (lane==0){
    float mean = __fdiv_rn(fin[0], 1024.0f);
    srt = rsqrtf(__fadd_rn(mean, 1e-6f));
  }
  __syncthreads();
  float r = srt;
  for (int i=lane; i<1024; i+=64)
    out[(size_t)row*DD + i] = __fmul_rn(__fmul_rn(xr[i], r), w[i]);
}

// ------- GEMM: strict k-ascending single-acc FMA; 128x(64*NQ) tile -------
// MODE: 0 = store, 1 = f32 += (residual), 2 = gelu (OCML erff) store.
template<int MODE, int NQ>
__global__ __launch_bounds__(256) void gemm_fast_k(const float* __restrict__ A,
    const float* __restrict__ B, float* __restrict__ C, int M, int N, int K){
  __shared__ float As[32][132];        // [k][m]
  __shared__ float Bs[32][64*NQ+4];    // [k][n]
  const int tid = threadIdx.x;
  const int tr = tid >> 4, tc = tid & 15;
  const int m0 = blockIdx.y*128, n0 = blockIdx.x*(64*NQ);

  float acc[8][4*NQ];
  #pragma unroll
  for (int i=0;i<8;i++)
    #pragma unroll
    for (int j=0;j<4*NQ;j++) acc[i][j] = 0.0f;

  for (int kk=0; kk<K; kk+=32){
    __syncthreads();
    #pragma unroll
    for (int it=0; it<4; ++it){        // A: 128 rows x 32 k -> As[k][m]
      int id = it*256 + tid;
      int row = id >> 3, f4 = id & 7;
      float4 v = *(const float4*)&A[(size_t)(m0+row)*K + kk + 4*f4];
      As[4*f4+0][row] = v.x; As[4*f4+1][row] = v.y;
      As[4*f4+2][row] = v.z; As[4*f4+3][row] = v.w;
    }
    #pragma unroll
    for (int it=0; it<2*NQ; ++it){     // B: 32 k x 64*NQ n
      int id = it*256 + tid;
      int r = id / (16*NQ), f4 = id % (16*NQ);
      *(float4*)&Bs[r][4*f4] = *(const float4*)&B[(size_t)(kk+r)*N + n0 + 4*f4];
    }
    __syncthreads();
    #pragma unroll 4
    for (int k=0; k<32; ++k){
      float4 a0 = *(const float4*)&As[k][4*tr];
      float4 a1 = *(const float4*)&As[k][64 + 4*tr];
      float av[8] = {a0.x,a0.y,a0.z,a0.w, a1.x,a1.y,a1.z,a1.w};
      float bv[4*NQ];
      {
        float4 b0 = *(const float4*)&Bs[k][4*tc];
        bv[0]=b0.x; bv[1]=b0.y; bv[2]=b0.z; bv[3]=b0.w;
        if (NQ==2){
          float4 b1 = *(const float4*)&Bs[k][64 + 4*tc];
          bv[4]=b1.x; bv[5]=b1.y; bv[6]=b1.z; bv[7]=b1.w;
        }
      }
      #pragma unroll
      for (int i=0;i<8;i++)
        #pragma unroll
        for (int j=0;j<4*NQ;j++)
          acc[i][j] = __builtin_fmaf(av[i], bv[j], acc[i][j]);
    }
  }
  #pragma unroll
  for (int i=0;i<8;i++){
    int row = m0 + (i>>2)*64 + 4*tr + (i&3);
    #pragma unroll
    for (int jq=0;jq<NQ;jq++){
      size_t off = (size_t)row*N + n0 + jq*64 + 4*tc;
      #pragma unroll
      for (int e=0;e<4;e++){
        float vv = acc[i][jq*4+e];
        if (MODE==0){
          C[off+e] = vv;
        } else if (MODE==1){
          C[off+e] = __fadd_rn(C[off+e], vv);
        } else {
          float t = __fdiv_rn(vv, 1.41421356f);
          float g = erff(t);
          C[off+e] = __fmul_rn(__fmul_rn(0.5f, vv), __fadd_rn(1.0f, g));
        }
      }
    }
  }
}

// ---------------- attention: 4 q/block, 128 threads, bit-exact ----------------
// Slot layout per q (same as R11): arr[0]=sink-exp, arr[1+kv]=score/exp/prob.
// Scores: d-ascending FMA then *0.125f. Denominator: strided-512 partials +
// tree64 pairing, lane-parallel. PV: kv-ascending single-acc chain per (q,d).
__global__ __launch_bounds__(128) void attn_fast_k(const float* __restrict__ qkv,
    const float* __restrict__ sink, float* __restrict__ y){
  __shared__ float arr[AQ][2052];
  __shared__ float Ks[64][65];
  __shared__ float Qs[AQ][64];
  __shared__ float p5[512];
  __shared__ float fin[64];
  __shared__ float mq[AQ];
  __shared__ float dq[AQ];
  const int tid = threadIdx.x;
  const int h = blockIdx.y, q0 = blockIdx.x*AQ;
  const int qmax = q0 + AQ - 1;
  const float snk = sink[h];

  for (int t=tid; t<AQ*64; t+=128){
    int i = t>>6, d = t&63;
    Qs[i][d] = qkv[(size_t)(q0+i)*3072 + h*64 + d];
  }
  #pragma unroll
  for (int i=0;i<AQ;i++)
    for (int s=tid; s<2052; s+=128) arr[i][s] = 0.0f;

  // ---- score phase: K chunks of 64 rows; thread = (kvl=tid&63, qh=tid>>6) ----
  const int kvl = tid & 63, qh = tid >> 6;          // qh: wave0 -> q0,q1; wave1 -> q2,q3
  float ml0 = -3.402823466e38f, ml1 = -3.402823466e38f;
  for (int base=0; base<=qmax; base+=64){
    __syncthreads();
    for (int t=tid; t<64*64; t+=128){
      int r = t>>6, c = t&63;
      int kr = base + r;
      Ks[r][c] = (kr < TT) ? qkv[(size_t)kr*3072 + 1024 + h*64 + c] : 0.0f;
    }
    __syncthreads();
    int kv = base + kvl;
    {
      int qi = 2*qh, qa = q0 + qi;
      if (kv <= qa){
        float s = 0.0f;
        #pragma unroll 8
        for (int d=0; d<64; ++d) s = __builtin_fmaf(Qs[qi][d], Ks[kvl][d], s);
        s = __fmul_rn(s, 0.125f);
        arr[qi][1+kv] = s;
        ml0 = fmaxf(ml0, s);
      }
    }
    {
      int qi = 2*qh+1, qa = q0 + qi;
      if (kv <= qa){
        float s = 0.0f;
        #pragma unroll 8
        for (int d=0; d<64; ++d) s = __builtin_fmaf(Qs[qi][d], Ks[kvl][d], s);
        s = __fmul_rn(s, 0.125f);
        arr[qi][1+kv] = s;
        ml1 = fmaxf(ml1, s);
      }
    }
  }
  #pragma unroll
  for (int off=32; off; off>>=1){
    ml0 = fmaxf(ml0, __shfl_xor(ml0, off, 64));
    ml1 = fmaxf(ml1, __shfl_xor(ml1, off, 64));
  }
  if (kvl==0){ mq[2*qh] = fmaxf(ml0, snk); mq[2*qh+1] = fmaxf(ml1, snk); }
  __syncthreads();

  // ---- exp (elementwise, OCML expf) ----
  #pragma unroll
  for (int i=0;i<AQ;i++){
    float m = mq[i]; int qa = q0+i;
    for (int kv=tid; kv<=qa; kv+=128)
      arr[i][1+kv] = expf(__fsub_rn(arr[i][1+kv], m));
  }
  if (tid < AQ) arr[tid][0] = expf(__fsub_rn(snk, mq[tid]));
  __syncthreads();

  // ---- denominator per q: strided-512 partials + tree64 pairing ----
  for (int i=0;i<AQ;i++){
    for (int t=tid; t<512; t+=128){
      float a = 0.0f;
      for (int s=t; s<2049; s+=512) a = __fadd_rn(a, arr[i][s]);
      p5[t] = a;
    }
    __syncthreads();
    #pragma unroll
    for (int off=32; off; off>>=1){
      for (int t=tid; t<8*off; t+=128){
        int wv = t/off, ii = t - wv*off;
        p5[64*wv+ii] = __fadd_rn(p5[64*wv+ii], p5[64*wv+ii+off]);
      }
      __syncthreads();
    }
    if (tid < 64) fin[tid] = (tid<8) ? p5[64*tid] : 0.0f;
    __syncthreads();
    #pragma unroll
    for (int off=32; off; off>>=1){
      if (tid<off) fin[tid] = __fadd_rn(fin[tid], fin[tid+off]);
      __syncthreads();
    }
    if (tid==0) dq[i] = fin[0];
    __syncthreads();
  }

  // ---- probs + left-shift by 1 slot (for aligned float4 PV reads) ----
  for (int i=0;i<AQ;i++){
    float den = dq[i]; int qa = q0+i;
    float tmp[17]; int c = 0;
    for (int kv=tid; kv<=qa; kv+=128) tmp[c++] = __fdiv_rn(arr[i][1+kv], den);
    __syncthreads();
    c = 0;
    for (int kv=tid; kv<=qa; kv+=128) arr[i][kv] = tmp[c++];
    __syncthreads();
  }

  // ---- PV: kv-ascending single-acc chain per (q,d); 2 rows/thread ----
  const int d = tid & 63, qg = tid >> 6;             // rows qg*2, qg*2+1
  const int r0 = qg*2, r1 = qg*2+1;
  const int qa0 = q0 + r0, qa1 = q0 + r1;
  float acc0 = 0.0f, acc1 = 0.0f;
  const float* vb = qkv + 2048 + h*64 + d;
  for (int kv4=0; kv4<=qmax; kv4+=4){
    float vv[4];
    #pragma unroll
    for (int e=0;e<4;e++) vv[e] = vb[(size_t)(kv4+e)*3072];
    float4 pa = *(const float4*)&arr[r0][kv4];
    float4 pb = *(const float4*)&arr[r1][kv4];
    float pra[4] = {pa.x,pa.y,pa.z,pa.w};
    float prb[4] = {pb.x,pb.y,pb.z,pb.w};
    #pragma unroll
    for (int e=0;e<4;e++){
      int kv = kv4+e;
      if (kv <= qa0) acc0 = __builtin_fmaf(pra[e], vv[e], acc0);
      if (kv <= qa1) acc1 = __builtin_fmaf(prb[e], vv[e], acc1);
    }
  }
  y[(size_t)(q0+r0)*DD + h*64 + d] = acc0;
  y[(size_t)(q0+r1)*DD + h*64 + d] = acc1;
}

// -------- abs top-k on f32 bits: exact radix select; zero in place --------
__global__ __launch_bounds__(256) void topk32_k(float* __restrict__ h,
    const int* __restrict__ kptr){
  const int row = blockIdx.x, tid = threadIdx.x;
  __shared__ int suf[256];
  __shared__ int s_sel, s_k;
  float* hr = h + (size_t)row*DMM;
  int kk = kptr[0];
  u32 prefix = 0u;
  for (int pass=0; pass<4; pass++){
    int shift = 24 - 8*pass;
    u32 hi_mask = pass ? (0xFFFFFFFFu << (shift+8)) : 0u;
    suf[tid] = 0;
    __syncthreads();
    for (int i=0;i<16;i++){
      u32 b = __float_as_uint(hr[tid + 256*i]) & 0x7fffffffu;
      if ((b & hi_mask) == prefix) atomicAdd(&suf[(b>>shift)&255], 1);
    }
    __syncthreads();
    for (int s=1;s<256;s<<=1){
      int v2 = (tid+s<256) ? suf[tid+s] : 0;
      __syncthreads();
      suf[tid] += v2;
      __syncthreads();
    }
    int nxt = (tid<255) ? suf[tid+1] : 0;
    if (suf[tid] >= kk && nxt < kk){ s_sel = tid; s_k = kk - nxt; }
    __syncthreads();
    prefix |= ((u32)s_sel) << shift;
    kk = s_k;
    __syncthreads();
  }
  for (int i=0;i<16;i++){
    int e = tid + 256*i;
    u32 b = __float_as_uint(hr[e]) & 0x7fffffffu;
    if (b < prefix) hr[e] = 0.0f;
  }
}

// ---------------- host launcher ----------------
extern "C" void kernel_launch(void* const* d_in, const int* in_sizes, int n_in,
                              void* d_out, int out_size, void* d_ws, size_t ws_size,
                              hipStream_t stream){
  const int*   idx  = (const int*)  d_in[0];
  const float* wte  = (const float*)d_in[1];
  const float* wpe  = (const float*)d_in[2];
  const float* ln1  = (const float*)d_in[3];
  const float* ln2  = (const float*)d_in[4];
  const float* Wa   = (const float*)d_in[5];
  const float* Wap  = (const float*)d_in[6];
  const float* Wf   = (const float*)d_in[7];
  const float* Wp   = (const float*)d_in[8];
  const float* sink = (const float*)d_in[9];
  const float* lnf  = (const float*)d_in[10];
  const float* lmw  = (const float*)d_in[11];
  const int*   kptr = (const int*)  d_in[12];
  (void)in_sizes; (void)n_in; (void)out_size; (void)ws_size;

  // ---- workspace: 80 MB, all fp32, no aliasing ----
  char* w = (char*)d_ws;
  float* x   = (float*)(w);                 // [0, 8M)
  float* xn  = (float*)(w + 8388608);       // [8M, 16M)
  float* qkv = (float*)(w + 16777216);      // [16M, 40M)
  float* y   = (float*)(w + 41943040);      // [40M, 48M)
  float* h   = (float*)(w + 50331648);      // [48M, 80M)

  embed32_k<<<TT, 256, 0, stream>>>(idx, wte, wpe, x);

  for (int l=0; l<4; l++){
    rms_xla_k<<<TT, 64, 0, stream>>>(x, ln1 + l*DD, xn);
    gemm_fast_k<0,2><<<dim3(3072/128, TT/128), 256, 0, stream>>>(xn, Wa + (size_t)l*1024*3072, qkv, TT, 3072, 1024);
    attn_fast_k<<<dim3(TT/AQ, HH), 128, 0, stream>>>(qkv, sink + l*HH, y);
    gemm_fast_k<1,1><<<dim3(1024/64, TT/128), 256, 0, stream>>>(y, Wap + (size_t)l*1024*1024, x, TT, 1024, 1024);
    rms_xla_k<<<TT, 64, 0, stream>>>(x, ln2 + l*DD, xn);
    gemm_fast_k<2,2><<<dim3(4096/128, TT/128), 256, 0, stream>>>(xn, Wf + (size_t)l*1024*4096, h, TT, 4096, 1024);
    topk32_k<<<TT, 256, 0, stream>>>(h, kptr);
    gemm_fast_k<1,1><<<dim3(1024/64, TT/128), 256, 0, stream>>>(h, Wp + (size_t)l*4096*1024, x, TT, 1024, 4096);
  }

  rms_xla_k<<<TT, 64, 0, stream>>>(x, lnf, xn);
  gemm_fast_k<0,2><<<dim3(VV/128, TT/128), 256, 0, stream>>>(xn, lmw, (float*)d_out, TT, VV, 1024);
}

// Round 14
// 8875.124 us; speedup vs baseline: 1.7226x; 1.7226x over previous
//
#include <hip/hip_runtime.h>

// SparseGPT forward on MI355X. Round 14: attention redesign, bit-exact to
// R11/R12/R13 (absmax 0.046875). 4 q/block, 256 threads; scores in registers
// (slot = tid+256k); denominator partials from registers with R11's exact
// strided-512 chain order; R13's pairing-preserving parallel tree; probs
// written to LDS once; PV = one wave per q, kv-ascending chain.
// GEMM/rmsnorm/topk unchanged from R13 (passing).

typedef unsigned int u32;

#define TT 2048
#define DD 1024
#define HH 16
#define DMM 4096
#define VV 32000
#define AQ 4

// ---------------- embedding ----------------
__global__ __launch_bounds__(256) void embed32_k(const int* __restrict__ idx,
    const float* __restrict__ wte, const float* __restrict__ wpe, float* __restrict__ x){
  int t = blockIdx.x, tid = threadIdx.x;
  int tok = idx[t];
  #pragma unroll
  for (int i=0;i<4;i++){
    int e = tid*4 + i;
    x[(size_t)t*DD + e] = __fadd_rn(wte[(size_t)tok*DD + e], wpe[(size_t)t*DD + e]);
  }
}

// ------- rmsnorm, XLA replica; reduce tree lane-parallel (same pairing) -------
__global__ __launch_bounds__(64) void rms_xla_k(const float* __restrict__ x,
    const float* __restrict__ w, float* __restrict__ out){
  __shared__ float sq[1024];
  __shared__ float p5[512];
  __shared__ float fin[64];
  __shared__ float srt;
  int row = blockIdx.x, lane = threadIdx.x;
  const float* xr = x + (size_t)row*DD;
  for (int i=lane; i<1024; i+=64){ float v = xr[i]; sq[i] = __fmul_rn(v,v); }
  __syncthreads();
  for (int t=lane; t<512; t+=64)
    p5[t] = __fadd_rn(sq[2*t], sq[2*t+1]);
  __syncthreads();
  #pragma unroll
  for (int off=32; off; off>>=1){
    for (int t=lane; t<8*off; t+=64){
      int wv = t/off, ii = t - wv*off;
      p5[64*wv+ii] = __fadd_rn(p5[64*wv+ii], p5[64*wv+ii+off]);
    }
    __syncthreads();
  }
  fin[lane] = (lane<8) ? p5[64*lane] : 0.0f;
  __syncthreads();
  #pragma unroll
  for (int off=32; off; off>>=1){
    if (lane<off) fin[lane] = __fadd_rn(fin[lane], fin[lane+off]);
    __syncthreads();
  }
  if (lane==0){
    float mean = __fdiv_rn(fin[0], 1024.0f);
    srt = rsqrtf(__fadd_rn(mean, 1e-6f));
  }
  __syncthreads();
  float r = srt;
  for (int i=lane; i<1024; i+=64)
    out[(size_t)row*DD + i] = __fmul_rn(__fmul_rn(xr[i], r), w[i]);
}

// ------- GEMM: strict k-ascending single-acc FMA; 128x(64*NQ) tile -------
template<int MODE, int NQ>
__global__ __launch_bounds__(256) void gemm_fast_k(const float* __restrict__ A,
    const float* __restrict__ B, float* __restrict__ C, int M, int N, int K){
  __shared__ float As[32][132];        // [k][m]
  __shared__ float Bs[32][64*NQ+4];    // [k][n]
  const int tid = threadIdx.x;
  const int tr = tid >> 4, tc = tid & 15;
  const int m0 = blockIdx.y*128, n0 = blockIdx.x*(64*NQ);

  float acc[8][4*NQ];
  #pragma unroll
  for (int i=0;i<8;i++)
    #pragma unroll
    for (int j=0;j<4*NQ;j++) acc[i][j] = 0.0f;

  for (int kk=0; kk<K; kk+=32){
    __syncthreads();
    #pragma unroll
    for (int it=0; it<4; ++it){        // A: 128 rows x 32 k -> As[k][m]
      int id = it*256 + tid;
      int row = id >> 3, f4 = id & 7;
      float4 v = *(const float4*)&A[(size_t)(m0+row)*K + kk + 4*f4];
      As[4*f4+0][row] = v.x; As[4*f4+1][row] = v.y;
      As[4*f4+2][row] = v.z; As[4*f4+3][row] = v.w;
    }
    #pragma unroll
    for (int it=0; it<2*NQ; ++it){     // B: 32 k x 64*NQ n
      int id = it*256 + tid;
      int r = id / (16*NQ), f4 = id % (16*NQ);
      *(float4*)&Bs[r][4*f4] = *(const float4*)&B[(size_t)(kk+r)*N + n0 + 4*f4];
    }
    __syncthreads();
    #pragma unroll 4
    for (int k=0; k<32; ++k){
      float4 a0 = *(const float4*)&As[k][4*tr];
      float4 a1 = *(const float4*)&As[k][64 + 4*tr];
      float av[8] = {a0.x,a0.y,a0.z,a0.w, a1.x,a1.y,a1.z,a1.w};
      float bv[4*NQ];
      {
        float4 b0 = *(const float4*)&Bs[k][4*tc];
        bv[0]=b0.x; bv[1]=b0.y; bv[2]=b0.z; bv[3]=b0.w;
        if (NQ==2){
          float4 b1 = *(const float4*)&Bs[k][64 + 4*tc];
          bv[4]=b1.x; bv[5]=b1.y; bv[6]=b1.z; bv[7]=b1.w;
        }
      }
      #pragma unroll
      for (int i=0;i<8;i++)
        #pragma unroll
        for (int j=0;j<4*NQ;j++)
          acc[i][j] = __builtin_fmaf(av[i], bv[j], acc[i][j]);
    }
  }
  #pragma unroll
  for (int i=0;i<8;i++){
    int row = m0 + (i>>2)*64 + 4*tr + (i&3);
    #pragma unroll
    for (int jq=0;jq<NQ;jq++){
      size_t off = (size_t)row*N + n0 + jq*64 + 4*tc;
      #pragma unroll
      for (int e=0;e<4;e++){
        float vv = acc[i][jq*4+e];
        if (MODE==0){
          C[off+e] = vv;
        } else if (MODE==1){
          C[off+e] = __fadd_rn(C[off+e], vv);
        } else {
          float t = __fdiv_rn(vv, 1.41421356f);
          float g = erff(t);
          C[off+e] = __fmul_rn(__fmul_rn(0.5f, vv), __fadd_rn(1.0f, g));
        }
      }
    }
  }
}

// ---------------- attention v3: 4 q/block, 256 threads, bit-exact ----------------
// Slot layout (R11): slot 0 = sink-exp, slot 1+kv = score/exp/prob.
// Thread owns slots {tid + 256k : k=0..8}. Scores & exp kept in registers.
// Denominator: partial[tid] = even-k chain, partial[tid+256] = odd-k chain
// (identical add order to R11's strided-512 loop); tree = R13's pairing.
// PV: wave qi, lane d; kv-ascending single-acc FMA chain.
__global__ __launch_bounds__(256) void attn_v3_k(const float* __restrict__ qkv,
    const float* __restrict__ sink, float* __restrict__ y){
  __shared__ float arr[AQ][2049];
  __shared__ float Qs[AQ][64];
  __shared__ float p5[AQ][512];
  __shared__ float fin[AQ][64];
  __shared__ float wmax[4][AQ];
  __shared__ float mq[AQ];
  __shared__ float dq[AQ];
  const int tid = threadIdx.x;
  const int lane = tid & 63, wvv = tid >> 6;
  const int h = blockIdx.y, q0 = blockIdx.x*AQ;
  const int qmax = q0 + AQ - 1;
  const float snk = sink[h];

  if (tid < AQ*64)
    Qs[tid>>6][tid&63] = qkv[(size_t)(q0 + (tid>>6))*3072 + h*64 + (tid&63)];
  __syncthreads();

  // ---- scores into registers (d-ascending FMA chain per (q,kv)) ----
  float sc[AQ][9];
  float ml[AQ];
  #pragma unroll
  for (int qi=0;qi<AQ;qi++) ml[qi] = -3.402823466e38f;

  #pragma unroll
  for (int k=0;k<9;k++){
    int s = tid + 256*k;
    #pragma unroll
    for (int qi=0;qi<AQ;qi++) sc[qi][k] = 0.0f;
    if (s >= 1 && s < 2049){
      int kv = s - 1;
      if (kv <= qmax){
        const float* kr = qkv + (size_t)kv*3072 + 1024 + h*64;
        float da[AQ];
        #pragma unroll
        for (int qi=0;qi<AQ;qi++) da[qi] = 0.0f;
        #pragma unroll 2
        for (int d0=0; d0<64; d0+=8){
          float4 ka = *(const float4*)&kr[d0];
          float4 kb = *(const float4*)&kr[d0+4];
          float kvv[8] = {ka.x,ka.y,ka.z,ka.w, kb.x,kb.y,kb.z,kb.w};
          #pragma unroll
          for (int qi=0;qi<AQ;qi++)
            #pragma unroll
            for (int e=0;e<8;e++)
              da[qi] = __builtin_fmaf(Qs[qi][d0+e], kvv[e], da[qi]);
        }
        #pragma unroll
        for (int qi=0;qi<AQ;qi++){
          float sv = __fmul_rn(da[qi], 0.125f);
          sc[qi][k] = sv;
          if (kv <= q0+qi) ml[qi] = fmaxf(ml[qi], sv);
        }
      }
    }
  }

  // ---- max per q (fmaxf: order-free exact) ----
  #pragma unroll
  for (int qi=0;qi<AQ;qi++){
    float m = ml[qi];
    #pragma unroll
    for (int off=1; off<64; off<<=1) m = fmaxf(m, __shfl_xor(m, off, 64));
    if (lane==0) wmax[wvv][qi] = m;
  }
  __syncthreads();
  if (tid < AQ){
    float m = fmaxf(fmaxf(wmax[0][tid], wmax[1][tid]),
                    fmaxf(wmax[2][tid], wmax[3][tid]));
    mq[tid] = fmaxf(m, snk);
  }
  __syncthreads();

  // ---- exp in registers (masked -> exact 0); sink-exp into thread0 slot0 ----
  #pragma unroll
  for (int k=0;k<9;k++){
    int s = tid + 256*k;
    #pragma unroll
    for (int qi=0;qi<AQ;qi++){
      bool valid = (s>=1) && (s<2049) && (s-1 <= q0+qi);
      sc[qi][k] = valid ? expf(__fsub_rn(sc[qi][k], mq[qi])) : 0.0f;
    }
  }
  if (tid==0){
    #pragma unroll
    for (int qi=0;qi<AQ;qi++) sc[qi][0] = expf(__fsub_rn(snk, mq[qi]));
  }

  // ---- denominator partials from registers (R11's exact chain order) ----
  #pragma unroll
  for (int qi=0;qi<AQ;qi++){
    float pe = 0.0f, po = 0.0f;
    #pragma unroll
    for (int k=0;k<9;k+=2) if (tid + 256*k < 2049) pe = __fadd_rn(pe, sc[qi][k]);
    #pragma unroll
    for (int k=1;k<9;k+=2) if (tid + 256*k < 2049) po = __fadd_rn(po, sc[qi][k]);
    p5[qi][tid]       = pe;
    p5[qi][tid + 256] = po;
  }
  __syncthreads();
  // tree64 over 8 groups of 64 per q (R13 pairing), batched across q
  #pragma unroll
  for (int off=32; off; off>>=1){
    for (int t=tid; t<AQ*8*off; t+=256){
      int qi = t/(8*off); int rem = t - qi*8*off;
      int g = rem/off, ii = rem - g*off;
      p5[qi][64*g+ii] = __fadd_rn(p5[qi][64*g+ii], p5[qi][64*g+ii+off]);
    }
    __syncthreads();
  }
  { int qi = tid>>6, i = tid&63; fin[qi][i] = (i<8) ? p5[qi][64*i] : 0.0f; }
  __syncthreads();
  #pragma unroll
  for (int off=32; off; off>>=1){
    for (int t=tid; t<AQ*off; t+=256){
      int qi = t/off, ii = t - qi*off;
      fin[qi][ii] = __fadd_rn(fin[qi][ii], fin[qi][ii+off]);
    }
    __syncthreads();
  }
  if (tid < AQ) dq[tid] = fin[tid][0];
  __syncthreads();

  // ---- probs -> LDS (single write per slot) ----
  #pragma unroll
  for (int k=0;k<9;k++){
    int s = tid + 256*k;
    if (s >= 1 && s < 2049){
      #pragma unroll
      for (int qi=0;qi<AQ;qi++)
        arr[qi][s] = (s-1 <= q0+qi) ? __fdiv_rn(sc[qi][k], dq[qi]) : 0.0f;
    }
  }
  __syncthreads();

  // ---- PV: wave = q, lane = d; kv-ascending single-acc chain ----
  const int qi = wvv, d = lane;
  const int qa = q0 + qi;
  float acc = 0.0f;
  const float* vb = qkv + 2048 + h*64 + d;
  int kv = 0;
  for (; kv + 8 <= qa + 1; kv += 8){
    #pragma unroll
    for (int e=0;e<8;e++)
      acc = __builtin_fmaf(arr[qi][1+kv+e], vb[(size_t)(kv+e)*3072], acc);
  }
  for (; kv <= qa; ++kv)
    acc = __builtin_fmaf(arr[qi][1+kv], vb[(size_t)kv*3072], acc);
  y[(size_t)qa*DD + h*64 + d] = acc;
}

// -------- abs top-k on f32 bits: exact radix select; zero in place --------
__global__ __launch_bounds__(256) void topk32_k(float* __restrict__ h,
    const int* __restrict__ kptr){
  const int row = blockIdx.x, tid = threadIdx.x;
  __shared__ int suf[256];
  __shared__ int s_sel, s_k;
  float* hr = h + (size_t)row*DMM;
  int kk = kptr[0];
  u32 prefix = 0u;
  for (int pass=0; pass<4; pass++){
    int shift = 24 - 8*pass;
    u32 hi_mask = pass ? (0xFFFFFFFFu << (shift+8)) : 0u;
    suf[tid] = 0;
    __syncthreads();
    for (int i=0;i<16;i++){
      u32 b = __float_as_uint(hr[tid + 256*i]) & 0x7fffffffu;
      if ((b & hi_mask) == prefix) atomicAdd(&suf[(b>>shift)&255], 1);
    }
    __syncthreads();
    for (int s=1;s<256;s<<=1){
      int v2 = (tid+s<256) ? suf[tid+s] : 0;
      __syncthreads();
      suf[tid] += v2;
      __syncthreads();
    }
    int nxt = (tid<255) ? suf[tid+1] : 0;
    if (suf[tid] >= kk && nxt < kk){ s_sel = tid; s_k = kk - nxt; }
    __syncthreads();
    prefix |= ((u32)s_sel) << shift;
    kk = s_k;
    __syncthreads();
  }
  for (int i=0;i<16;i++){
    int e = tid + 256*i;
    u32 b = __float_as_uint(hr[e]) & 0x7fffffffu;
    if (b < prefix) hr[e] = 0.0f;
  }
}

// ---------------- host launcher ----------------
extern "C" void kernel_launch(void* const* d_in, const int* in_sizes, int n_in,
                              void* d_out, int out_size, void* d_ws, size_t ws_size,
                              hipStream_t stream){
  const int*   idx  = (const int*)  d_in[0];
  const float* wte  = (const float*)d_in[1];
  const float* wpe  = (const float*)d_in[2];
  const float* ln1  = (const float*)d_in[3];
  const float* ln2  = (const float*)d_in[4];
  const float* Wa   = (const float*)d_in[5];
  const float* Wap  = (const float*)d_in[6];
  const float* Wf   = (const float*)d_in[7];
  const float* Wp   = (const float*)d_in[8];
  const float* sink = (const float*)d_in[9];
  const float* lnf  = (const float*)d_in[10];
  const float* lmw  = (const float*)d_in[11];
  const int*   kptr = (const int*)  d_in[12];
  (void)in_sizes; (void)n_in; (void)out_size; (void)ws_size;

  // ---- workspace: 80 MB, all fp32, no aliasing ----
  char* w = (char*)d_ws;
  float* x   = (float*)(w);                 // [0, 8M)
  float* xn  = (float*)(w + 8388608);       // [8M, 16M)
  float* qkv = (float*)(w + 16777216);      // [16M, 40M)
  float* y   = (float*)(w + 41943040);      // [40M, 48M)
  float* h   = (float*)(w + 50331648);      // [48M, 80M)

  embed32_k<<<TT, 256, 0, stream>>>(idx, wte, wpe, x);

  for (int l=0; l<4; l++){
    rms_xla_k<<<TT, 64, 0, stream>>>(x, ln1 + l*DD, xn);
    gemm_fast_k<0,2><<<dim3(3072/128, TT/128), 256, 0, stream>>>(xn, Wa + (size_t)l*1024*3072, qkv, TT, 3072, 1024);
    attn_v3_k<<<dim3(TT/AQ, HH), 256, 0, stream>>>(qkv, sink + l*HH, y);
    gemm_fast_k<1,1><<<dim3(1024/64, TT/128), 256, 0, stream>>>(y, Wap + (size_t)l*1024*1024, x, TT, 1024, 1024);
    rms_xla_k<<<TT, 64, 0, stream>>>(x, ln2 + l*DD, xn);
    gemm_fast_k<2,2><<<dim3(4096/128, TT/128), 256, 0, stream>>>(xn, Wf + (size_t)l*1024*4096, h, TT, 4096, 1024);
    topk32_k<<<TT, 256, 0, stream>>>(h, kptr);
    gemm_fast_k<1,1><<<dim3(1024/64, TT/128), 256, 0, stream>>>(h, Wp + (size_t)l*4096*1024, x, TT, 1024, 4096);
  }

  rms_xla_k<<<TT, 64, 0, stream>>>(x, lnf, xn);
  gemm_fast_k<0,2><<<dim3(VV/128, TT/128), 256, 0, stream>>>(xn, lmw, (float*)d_out, TT, VV, 1024);
}

// Round 15
// 8001.497 us; speedup vs baseline: 1.9107x; 1.1092x over previous
//
#include <hip/hip_runtime.h>

// SparseGPT forward on MI355X. Round 15: bit-exact perf round.
// - attn v5: Q in registers, LDS K-chunks (b128 floor), causal chunk count,
//   R11-exact chain orders everywhere. 50KB LDS (p5/fin union Ks).
// - GEMM: BK=16 double-buffered, 1 barrier/iter, prefetch-to-regs.
// All per-output fp32 op orders identical to passing R11-R14 (absmax 0.046875).

typedef unsigned int u32;

#define TT 2048
#define DD 1024
#define HH 16
#define DMM 4096
#define VV 32000
#define AQ 4

// ---------------- embedding ----------------
__global__ __launch_bounds__(256) void embed32_k(const int* __restrict__ idx,
    const float* __restrict__ wte, const float* __restrict__ wpe, float* __restrict__ x){
  int t = blockIdx.x, tid = threadIdx.x;
  int tok = idx[t];
  #pragma unroll
  for (int i=0;i<4;i++){
    int e = tid*4 + i;
    x[(size_t)t*DD + e] = __fadd_rn(wte[(size_t)tok*DD + e], wpe[(size_t)t*DD + e]);
  }
}

// ------- rmsnorm, XLA replica; lane-parallel tree (same pairing) -------
__global__ __launch_bounds__(64) void rms_xla_k(const float* __restrict__ x,
    const float* __restrict__ w, float* __restrict__ out){
  __shared__ float sq[1024];
  __shared__ float p5[512];
  __shared__ float fin[64];
  __shared__ float srt;
  int row = blockIdx.x, lane = threadIdx.x;
  const float* xr = x + (size_t)row*DD;
  for (int i=lane; i<1024; i+=64){ float v = xr[i]; sq[i] = __fmul_rn(v,v); }
  __syncthreads();
  for (int t=lane; t<512; t+=64)
    p5[t] = __fadd_rn(sq[2*t], sq[2*t+1]);
  __syncthreads();
  #pragma unroll
  for (int off=32; off; off>>=1){
    for (int t=lane; t<8*off; t+=64){
      int wv = t/off, ii = t - wv*off;
      p5[64*wv+ii] = __fadd_rn(p5[64*wv+ii], p5[64*wv+ii+off]);
    }
    __syncthreads();
  }
  fin[lane] = (lane<8) ? p5[64*lane] : 0.0f;
  __syncthreads();
  #pragma unroll
  for (int off=32; off; off>>=1){
    if (lane<off) fin[lane] = __fadd_rn(fin[lane], fin[lane+off]);
    __syncthreads();
  }
  if (lane==0){
    float mean = __fdiv_rn(fin[0], 1024.0f);
    srt = rsqrtf(__fadd_rn(mean, 1e-6f));
  }
  __syncthreads();
  float r = srt;
  for (int i=lane; i<1024; i+=64)
    out[(size_t)row*DD + i] = __fmul_rn(__fmul_rn(xr[i], r), w[i]);
}

// ------- GEMM: strict k-ascending single-acc FMA; BK=16 double-buffered -------
// MODE: 0 = store, 1 = f32 += (residual), 2 = gelu (OCML erff) store.
template<int MODE, int NQ>
__global__ __launch_bounds__(256) void gemm_db_k(const float* __restrict__ A,
    const float* __restrict__ B, float* __restrict__ C, int M, int N, int K){
  __shared__ float As[2][16][132];          // [buf][k][m]
  __shared__ float Bs[2][16][64*NQ+4];      // [buf][k][n]
  const int tid = threadIdx.x;
  const int tr = tid >> 4, tc = tid & 15;
  const int m0 = blockIdx.y*128, n0 = blockIdx.x*(64*NQ);

  // staging maps
  const int ar0 = tid >> 2,       af0 = tid & 3;        // A it=0: rows 0..63
  const int ar1 = (256+tid) >> 2, af1 = tid & 3;        // A it=1: rows 64..127
  float acc[8][4*NQ];
  #pragma unroll
  for (int i=0;i<8;i++)
    #pragma unroll
    for (int j=0;j<4*NQ;j++) acc[i][j] = 0.0f;

  const int niter = K >> 4;
  // prologue: stage tile 0 into buf 0
  {
    float4 va0 = *(const float4*)&A[(size_t)(m0+ar0)*K + 4*af0];
    float4 va1 = *(const float4*)&A[(size_t)(m0+ar1)*K + 4*af1];
    As[0][4*af0+0][ar0]=va0.x; As[0][4*af0+1][ar0]=va0.y; As[0][4*af0+2][ar0]=va0.z; As[0][4*af0+3][ar0]=va0.w;
    As[0][4*af1+0][ar1]=va1.x; As[0][4*af1+1][ar1]=va1.y; As[0][4*af1+2][ar1]=va1.z; As[0][4*af1+3][ar1]=va1.w;
    if (NQ==2){
      int r0 = tid>>5, c40 = tid&31;
      int r1 = (256+tid)>>5, c41 = tid&31;
      *(float4*)&Bs[0][r0][4*c40] = *(const float4*)&B[(size_t)r0*N + n0 + 4*c40];
      *(float4*)&Bs[0][r1][4*c41] = *(const float4*)&B[(size_t)r1*N + n0 + 4*c41];
    } else {
      int r0 = tid>>4, c40 = tid&15;
      *(float4*)&Bs[0][r0][4*c40] = *(const float4*)&B[(size_t)r0*N + n0 + 4*c40];
    }
  }
  __syncthreads();

  for (int t=0; t<niter; ++t){
    const int cur = t & 1;
    // prefetch next tile to regs
    float4 va0, va1, vb0, vb1;
    if (t+1 < niter){
      int kk = (t+1) << 4;
      va0 = *(const float4*)&A[(size_t)(m0+ar0)*K + kk + 4*af0];
      va1 = *(const float4*)&A[(size_t)(m0+ar1)*K + kk + 4*af1];
      if (NQ==2){
        int r0 = tid>>5, c40 = tid&31;
        int r1 = (256+tid)>>5;
        vb0 = *(const float4*)&B[(size_t)(kk+r0)*N + n0 + 4*c40];
        vb1 = *(const float4*)&B[(size_t)(kk+r1)*N + n0 + 4*c40];
      } else {
        int r0 = tid>>4, c40 = tid&15;
        vb0 = *(const float4*)&B[(size_t)(kk+r0)*N + n0 + 4*c40];
      }
    }
    // compute 16 k-steps from buf cur (k ascending -> exact chain order)
    #pragma unroll 4
    for (int k=0; k<16; ++k){
      float4 a0 = *(const float4*)&As[cur][k][4*tr];
      float4 a1 = *(const float4*)&As[cur][k][64 + 4*tr];
      float4 b0 = *(const float4*)&Bs[cur][k][4*tc];
      float av[8] = {a0.x,a0.y,a0.z,a0.w, a1.x,a1.y,a1.z,a1.w};
      float bv[4*NQ];
      bv[0]=b0.x; bv[1]=b0.y; bv[2]=b0.z; bv[3]=b0.w;
      if (NQ==2){
        float4 b1 = *(const float4*)&Bs[cur][k][64 + 4*tc];
        bv[4]=b1.x; bv[5]=b1.y; bv[6]=b1.z; bv[7]=b1.w;
      }
      #pragma unroll
      for (int i=0;i<8;i++)
        #pragma unroll
        for (int j=0;j<4*NQ;j++)
          acc[i][j] = __builtin_fmaf(av[i], bv[j], acc[i][j]);
    }
    // write prefetched tile into the other buffer
    if (t+1 < niter){
      const int nxt = cur ^ 1;
      As[nxt][4*af0+0][ar0]=va0.x; As[nxt][4*af0+1][ar0]=va0.y; As[nxt][4*af0+2][ar0]=va0.z; As[nxt][4*af0+3][ar0]=va0.w;
      As[nxt][4*af1+0][ar1]=va1.x; As[nxt][4*af1+1][ar1]=va1.y; As[nxt][4*af1+2][ar1]=va1.z; As[nxt][4*af1+3][ar1]=va1.w;
      if (NQ==2){
        int r0 = tid>>5, c40 = tid&31;
        int r1 = (256+tid)>>5;
        *(float4*)&Bs[nxt][r0][4*c40] = vb0;
        *(float4*)&Bs[nxt][r1][4*c40] = vb1;
      } else {
        int r0 = tid>>4, c40 = tid&15;
        *(float4*)&Bs[nxt][r0][4*c40] = vb0;
      }
    }
    __syncthreads();
  }

  #pragma unroll
  for (int i=0;i<8;i++){
    int row = m0 + (i>>2)*64 + 4*tr + (i&3);
    #pragma unroll
    for (int jq=0;jq<NQ;jq++){
      size_t off = (size_t)row*N + n0 + jq*64 + 4*tc;
      #pragma unroll
      for (int e=0;e<4;e++){
        float vv = acc[i][jq*4+e];
        if (MODE==0){
          C[off+e] = vv;
        } else if (MODE==1){
          C[off+e] = __fadd_rn(C[off+e], vv);
        } else {
          float t2 = __fdiv_rn(vv, 1.41421356f);
          float g = erff(t2);
          C[off+e] = __fmul_rn(__fmul_rn(0.5f, vv), __fadd_rn(1.0f, g));
        }
      }
    }
  }
}

// ---------------- attention v5: Q-in-regs, LDS K-chunks, bit-exact ----------------
// Wave w owns q = q0+w. Slot layout (R11): arr[qi][0]=sink-exp, [1+kv]=val.
__global__ __launch_bounds__(256) void attn_v5_k(const float* __restrict__ qkv,
    const float* __restrict__ sink, float* __restrict__ y){
  __shared__ float arr[AQ][2052];       // 32.8KB
  __shared__ float uks[64*68];          // 17.4KB: Ks[64][68] then p5[4][512]+fin[4][64]
  __shared__ float mq[AQ];
  __shared__ float dq[AQ];
  float (*Ks)[68]   = (float(*)[68])uks;
  float (*p5)[512]  = (float(*)[512])uks;
  float (*fin)[64]  = (float(*)[64])(uks + AQ*512);
  const int tid = threadIdx.x;
  const int lane = tid & 63, wv = tid >> 6;
  const int h = blockIdx.y, q0 = blockIdx.x*AQ;
  const int qa_w = q0 + wv;             // this wave's q
  const float snk = sink[h];

  // zero-init arr (masked slots must be exact 0)
  #pragma unroll
  for (int qi=0;qi<AQ;qi++)
    for (int s=tid; s<2052; s+=256) arr[qi][s] = 0.0f;

  // preload Q row (wave-uniform address -> scalarized); 64 regs
  float qv[64];
  {
    const float* qr = qkv + (size_t)qa_w*3072 + h*64;
    #pragma unroll
    for (int c4=0;c4<16;c4++){
      float4 v = *(const float4*)&qr[4*c4];
      qv[4*c4]=v.x; qv[4*c4+1]=v.y; qv[4*c4+2]=v.z; qv[4*c4+3]=v.w;
    }
  }

  // ---- scores: K chunks of 64 rows staged to LDS ----
  float ml = -3.402823466e38f;
  const int qmax = q0 + AQ - 1;
  for (int base=0; base<=qmax; base+=64){
    __syncthreads();                    // Ks reuse from prev chunk
    #pragma unroll
    for (int it=0; it<4; ++it){         // stage: 64 rows x 64 floats
      int id = it*256 + tid;
      int r = id >> 4, c4 = id & 15;
      int kr = base + r;
      if (kr < TT)
        *(float4*)&Ks[r][4*c4] = *(const float4*)&qkv[(size_t)kr*3072 + 1024 + h*64 + 4*c4];
    }
    __syncthreads();
    int kv = base + lane;
    if (kv <= qa_w){
      float s = 0.0f;
      #pragma unroll
      for (int c4=0;c4<16;c4++){        // d-ascending FMA chain (R11 order)
        float4 kf = *(const float4*)&Ks[lane][4*c4];
        s = __builtin_fmaf(qv[4*c4  ], kf.x, s);
        s = __builtin_fmaf(qv[4*c4+1], kf.y, s);
        s = __builtin_fmaf(qv[4*c4+2], kf.z, s);
        s = __builtin_fmaf(qv[4*c4+3], kf.w, s);
      }
      s = __fmul_rn(s, 0.125f);
      arr[wv][1+kv] = s;
      ml = fmaxf(ml, s);
    }
  }
  // wave max (order-free) + sink
  #pragma unroll
  for (int off=1; off<64; off<<=1) ml = fmaxf(ml, __shfl_xor(ml, off, 64));
  if (lane==0) mq[wv] = fmaxf(ml, snk);
  __syncthreads();

  // ---- exp (OCML expf), masked slots stay 0; sink-exp into slot 0 ----
  #pragma unroll
  for (int qi=0;qi<AQ;qi++){
    float m = mq[qi]; int qa = q0+qi;
    for (int s=tid; s<2049; s+=256){
      if (s >= 1 && s-1 <= qa)
        arr[qi][s] = expf(__fsub_rn(arr[qi][s], m));
    }
  }
  if (tid < AQ) arr[tid][0] = expf(__fsub_rn(snk, mq[tid]));
  __syncthreads();

  // ---- denominator: R11 strided-512 chains + batched pairing tree ----
  #pragma unroll
  for (int m2=0; m2<8; ++m2){
    int flat = m2*256 + tid;            // 0..2047
    int qi = flat >> 9, t = flat & 511;
    float a = 0.0f;
    for (int s=t; s<2049; s+=512) a = __fadd_rn(a, arr[qi][s]);
    p5[qi][t] = a;
  }
  __syncthreads();
  #pragma unroll
  for (int off=32; off; off>>=1){
    for (int t=tid; t<AQ*8*off; t+=256){
      int qi = t/(8*off); int rem = t - qi*8*off;
      int g = rem/off, ii = rem - g*off;
      p5[qi][64*g+ii] = __fadd_rn(p5[qi][64*g+ii], p5[qi][64*g+ii+off]);
    }
    __syncthreads();
  }
  { int qi = tid>>6, i = tid&63; fin[qi][i] = (i<8) ? p5[qi][64*i] : 0.0f; }
  __syncthreads();
  #pragma unroll
  for (int off=32; off; off>>=1){
    for (int t=tid; t<AQ*off; t+=256){
      int qi = t/off, ii = t - qi*off;
      fin[qi][ii] = __fadd_rn(fin[qi][ii], fin[qi][ii+off]);
    }
    __syncthreads();
  }
  if (tid < AQ) dq[tid] = fin[tid][0];
  __syncthreads();

  // ---- probs in place ----
  #pragma unroll
  for (int qi=0;qi<AQ;qi++){
    float den = dq[qi]; int qa = q0+qi;
    for (int s=tid; s<2049; s+=256)
      if (s >= 1 && s-1 <= qa)
        arr[qi][s] = __fdiv_rn(arr[qi][s], den);
  }
  __syncthreads();

  // ---- PV: wave = q, lane = d; kv-ascending single-acc chain ----
  const int d = lane;
  float acc = 0.0f;
  const float* vb = qkv + 2048 + h*64 + d;
  int kv = 0;
  for (; kv + 8 <= qa_w + 1; kv += 8){
    #pragma unroll
    for (int e=0;e<8;e++)
      acc = __builtin_fmaf(arr[wv][1+kv+e], vb[(size_t)(kv+e)*3072], acc);
  }
  for (; kv <= qa_w; ++kv)
    acc = __builtin_fmaf(arr[wv][1+kv], vb[(size_t)kv*3072], acc);
  y[(size_t)qa_w*DD + h*64 + d] = acc;
}

// -------- abs top-k on f32 bits: exact radix select; zero in place --------
__global__ __launch_bounds__(256) void topk32_k(float* __restrict__ h,
    const int* __restrict__ kptr){
  const int row = blockIdx.x, tid = threadIdx.x;
  __shared__ int suf[256];
  __shared__ int s_sel, s_k;
  float* hr = h + (size_t)row*DMM;
  int kk = kptr[0];
  u32 prefix = 0u;
  for (int pass=0; pass<4; pass++){
    int shift = 24 - 8*pass;
    u32 hi_mask = pass ? (0xFFFFFFFFu << (shift+8)) : 0u;
    suf[tid] = 0;
    __syncthreads();
    for (int i=0;i<16;i++){
      u32 b = __float_as_uint(hr[tid + 256*i]) & 0x7fffffffu;
      if ((b & hi_mask) == prefix) atomicAdd(&suf[(b>>shift)&255], 1);
    }
    __syncthreads();
    for (int s=1;s<256;s<<=1){
      int v2 = (tid+s<256) ? suf[tid+s] : 0;
      __syncthreads();
      suf[tid] += v2;
      __syncthreads();
    }
    int nxt = (tid<255) ? suf[tid+1] : 0;
    if (suf[tid] >= kk && nxt < kk){ s_sel = tid; s_k = kk - nxt; }
    __syncthreads();
    prefix |= ((u32)s_sel) << shift;
    kk = s_k;
    __syncthreads();
  }
  for (int i=0;i<16;i++){
    int e = tid + 256*i;
    u32 b = __float_as_uint(hr[e]) & 0x7fffffffu;
    if (b < prefix) hr[e] = 0.0f;
  }
}

// ---------------- host launcher ----------------
extern "C" void kernel_launch(void* const* d_in, const int* in_sizes, int n_in,
                              void* d_out, int out_size, void* d_ws, size_t ws_size,
                              hipStream_t stream){
  const int*   idx  = (const int*)  d_in[0];
  const float* wte  = (const float*)d_in[1];
  const float* wpe  = (const float*)d_in[2];
  const float* ln1  = (const float*)d_in[3];
  const float* ln2  = (const float*)d_in[4];
  const float* Wa   = (const float*)d_in[5];
  const float* Wap  = (const float*)d_in[6];
  const float* Wf   = (const float*)d_in[7];
  const float* Wp   = (const float*)d_in[8];
  const float* sink = (const float*)d_in[9];
  const float* lnf  = (const float*)d_in[10];
  const float* lmw  = (const float*)d_in[11];
  const int*   kptr = (const int*)  d_in[12];
  (void)in_sizes; (void)n_in; (void)out_size; (void)ws_size;

  // ---- workspace: 80 MB, all fp32, no aliasing ----
  char* w = (char*)d_ws;
  float* x   = (float*)(w);                 // [0, 8M)
  float* xn  = (float*)(w + 8388608);       // [8M, 16M)
  float* qkv = (float*)(w + 16777216);      // [16M, 40M)
  float* y   = (float*)(w + 41943040);      // [40M, 48M)
  float* h   = (float*)(w + 50331648);      // [48M, 80M)

  embed32_k<<<TT, 256, 0, stream>>>(idx, wte, wpe, x);

  for (int l=0; l<4; l++){
    rms_xla_k<<<TT, 64, 0, stream>>>(x, ln1 + l*DD, xn);
    gemm_db_k<0,2><<<dim3(3072/128, TT/128), 256, 0, stream>>>(xn, Wa + (size_t)l*1024*3072, qkv, TT, 3072, 1024);
    attn_v5_k<<<dim3(TT/AQ, HH), 256, 0, stream>>>(qkv, sink + l*HH, y);
    gemm_db_k<1,1><<<dim3(1024/64, TT/128), 256, 0, stream>>>(y, Wap + (size_t)l*1024*1024, x, TT, 1024, 1024);
    rms_xla_k<<<TT, 64, 0, stream>>>(x, ln2 + l*DD, xn);
    gemm_db_k<2,2><<<dim3(4096/128, TT/128), 256, 0, stream>>>(xn, Wf + (size_t)l*1024*4096, h, TT, 4096, 1024);
    topk32_k<<<TT, 256, 0, stream>>>(h, kptr);
    gemm_db_k<1,1><<<dim3(1024/64, TT/128), 256, 0, stream>>>(h, Wp + (size_t)l*4096*1024, x, TT, 1024, 4096);
  }

  rms_xla_k<<<TT, 64, 0, stream>>>(x, lnf, xn);
  gemm_db_k<0,2><<<dim3(VV/128, TT/128), 256, 0, stream>>>(xn, lmw, (float*)d_out, TT, VV, 1024);
}

// Round 16
// 7866.416 us; speedup vs baseline: 1.9435x; 1.0172x over previous
//
#include <hip/hip_runtime.h>

// SparseGPT forward on MI355X. Round 16: bit-exact perf round.
// - attn v6: wave-local softmax (shfl trees, R11-exact pairing), V staged in
//   LDS chunks (L2 traffic /4), kv-ascending chains preserved.
// - GEMM: R15's BK=16 double-buffered (passing, 84% VALU).
// All per-output fp32 op orders identical to passing R11-R15 (absmax 0.046875).

typedef unsigned int u32;

#define TT 2048
#define DD 1024
#define HH 16
#define DMM 4096
#define VV 32000
#define AQ 4

// ---------------- embedding ----------------
__global__ __launch_bounds__(256) void embed32_k(const int* __restrict__ idx,
    const float* __restrict__ wte, const float* __restrict__ wpe, float* __restrict__ x){
  int t = blockIdx.x, tid = threadIdx.x;
  int tok = idx[t];
  #pragma unroll
  for (int i=0;i<4;i++){
    int e = tid*4 + i;
    x[(size_t)t*DD + e] = __fadd_rn(wte[(size_t)tok*DD + e], wpe[(size_t)t*DD + e]);
  }
}

// ------- rmsnorm, XLA replica; lane-parallel tree (same pairing) -------
__global__ __launch_bounds__(64) void rms_xla_k(const float* __restrict__ x,
    const float* __restrict__ w, float* __restrict__ out){
  __shared__ float sq[1024];
  __shared__ float p5[512];
  __shared__ float fin[64];
  __shared__ float srt;
  int row = blockIdx.x, lane = threadIdx.x;
  const float* xr = x + (size_t)row*DD;
  for (int i=lane; i<1024; i+=64){ float v = xr[i]; sq[i] = __fmul_rn(v,v); }
  __syncthreads();
  for (int t=lane; t<512; t+=64)
    p5[t] = __fadd_rn(sq[2*t], sq[2*t+1]);
  __syncthreads();
  #pragma unroll
  for (int off=32; off; off>>=1){
    for (int t=lane; t<8*off; t+=64){
      int wv = t/off, ii = t - wv*off;
      p5[64*wv+ii] = __fadd_rn(p5[64*wv+ii], p5[64*wv+ii+off]);
    }
    __syncthreads();
  }
  fin[lane] = (lane<8) ? p5[64*lane] : 0.0f;
  __syncthreads();
  #pragma unroll
  for (int off=32; off; off>>=1){
    if (lane<off) fin[lane] = __fadd_rn(fin[lane], fin[lane+off]);
    __syncthreads();
  }
  if (lane==0){
    float mean = __fdiv_rn(fin[0], 1024.0f);
    srt = rsqrtf(__fadd_rn(mean, 1e-6f));
  }
  __syncthreads();
  float r = srt;
  for (int i=lane; i<1024; i+=64)
    out[(size_t)row*DD + i] = __fmul_rn(__fmul_rn(xr[i], r), w[i]);
}

// ------- GEMM: strict k-ascending single-acc FMA; BK=16 double-buffered -------
template<int MODE, int NQ>
__global__ __launch_bounds__(256) void gemm_db_k(const float* __restrict__ A,
    const float* __restrict__ B, float* __restrict__ C, int M, int N, int K){
  __shared__ float As[2][16][132];          // [buf][k][m]
  __shared__ float Bs[2][16][64*NQ+4];      // [buf][k][n]
  const int tid = threadIdx.x;
  const int tr = tid >> 4, tc = tid & 15;
  const int m0 = blockIdx.y*128, n0 = blockIdx.x*(64*NQ);

  const int ar0 = tid >> 2,       af0 = tid & 3;
  const int ar1 = (256+tid) >> 2, af1 = tid & 3;
  float acc[8][4*NQ];
  #pragma unroll
  for (int i=0;i<8;i++)
    #pragma unroll
    for (int j=0;j<4*NQ;j++) acc[i][j] = 0.0f;

  const int niter = K >> 4;
  {
    float4 va0 = *(const float4*)&A[(size_t)(m0+ar0)*K + 4*af0];
    float4 va1 = *(const float4*)&A[(size_t)(m0+ar1)*K + 4*af1];
    As[0][4*af0+0][ar0]=va0.x; As[0][4*af0+1][ar0]=va0.y; As[0][4*af0+2][ar0]=va0.z; As[0][4*af0+3][ar0]=va0.w;
    As[0][4*af1+0][ar1]=va1.x; As[0][4*af1+1][ar1]=va1.y; As[0][4*af1+2][ar1]=va1.z; As[0][4*af1+3][ar1]=va1.w;
    if (NQ==2){
      int r0 = tid>>5, c40 = tid&31;
      int r1 = (256+tid)>>5, c41 = tid&31;
      *(float4*)&Bs[0][r0][4*c40] = *(const float4*)&B[(size_t)r0*N + n0 + 4*c40];
      *(float4*)&Bs[0][r1][4*c41] = *(const float4*)&B[(size_t)r1*N + n0 + 4*c41];
    } else {
      int r0 = tid>>4, c40 = tid&15;
      *(float4*)&Bs[0][r0][4*c40] = *(const float4*)&B[(size_t)r0*N + n0 + 4*c40];
    }
  }
  __syncthreads();

  for (int t=0; t<niter; ++t){
    const int cur = t & 1;
    float4 va0, va1, vb0, vb1;
    if (t+1 < niter){
      int kk = (t+1) << 4;
      va0 = *(const float4*)&A[(size_t)(m0+ar0)*K + kk + 4*af0];
      va1 = *(const float4*)&A[(size_t)(m0+ar1)*K + kk + 4*af1];
      if (NQ==2){
        int r0 = tid>>5, c40 = tid&31;
        int r1 = (256+tid)>>5;
        vb0 = *(const float4*)&B[(size_t)(kk+r0)*N + n0 + 4*c40];
        vb1 = *(const float4*)&B[(size_t)(kk+r1)*N + n0 + 4*c40];
      } else {
        int r0 = tid>>4, c40 = tid&15;
        vb0 = *(const float4*)&B[(size_t)(kk+r0)*N + n0 + 4*c40];
      }
    }
    #pragma unroll 4
    for (int k=0; k<16; ++k){
      float4 a0 = *(const float4*)&As[cur][k][4*tr];
      float4 a1 = *(const float4*)&As[cur][k][64 + 4*tr];
      float4 b0 = *(const float4*)&Bs[cur][k][4*tc];
      float av[8] = {a0.x,a0.y,a0.z,a0.w, a1.x,a1.y,a1.z,a1.w};
      float bv[4*NQ];
      bv[0]=b0.x; bv[1]=b0.y; bv[2]=b0.z; bv[3]=b0.w;
      if (NQ==2){
        float4 b1 = *(const float4*)&Bs[cur][k][64 + 4*tc];
        bv[4]=b1.x; bv[5]=b1.y; bv[6]=b1.z; bv[7]=b1.w;
      }
      #pragma unroll
      for (int i=0;i<8;i++)
        #pragma unroll
        for (int j=0;j<4*NQ;j++)
          acc[i][j] = __builtin_fmaf(av[i], bv[j], acc[i][j]);
    }
    if (t+1 < niter){
      const int nxt = cur ^ 1;
      As[nxt][4*af0+0][ar0]=va0.x; As[nxt][4*af0+1][ar0]=va0.y; As[nxt][4*af0+2][ar0]=va0.z; As[nxt][4*af0+3][ar0]=va0.w;
      As[nxt][4*af1+0][ar1]=va1.x; As[nxt][4*af1+1][ar1]=va1.y; As[nxt][4*af1+2][ar1]=va1.z; As[nxt][4*af1+3][ar1]=va1.w;
      if (NQ==2){
        int r0 = tid>>5, c40 = tid&31;
        int r1 = (256+tid)>>5;
        *(float4*)&Bs[nxt][r0][4*c40] = vb0;
        *(float4*)&Bs[nxt][r1][4*c40] = vb1;
      } else {
        int r0 = tid>>4, c40 = tid&15;
        *(float4*)&Bs[nxt][r0][4*c40] = vb0;
      }
    }
    __syncthreads();
  }

  #pragma unroll
  for (int i=0;i<8;i++){
    int row = m0 + (i>>2)*64 + 4*tr + (i&3);
    #pragma unroll
    for (int jq=0;jq<NQ;jq++){
      size_t off = (size_t)row*N + n0 + jq*64 + 4*tc;
      #pragma unroll
      for (int e=0;e<4;e++){
        float vv = acc[i][jq*4+e];
        if (MODE==0){
          C[off+e] = vv;
        } else if (MODE==1){
          C[off+e] = __fadd_rn(C[off+e], vv);
        } else {
          float t2 = __fdiv_rn(vv, 1.41421356f);
          float g = erff(t2);
          C[off+e] = __fmul_rn(__fmul_rn(0.5f, vv), __fadd_rn(1.0f, g));
        }
      }
    }
  }
}

// ---------------- attention v6: wave-local softmax + staged V, bit-exact ----------------
// Wave w owns q = q0+w. Slot layout (R11): arr[w][0]=sink-exp, [1+kv]=val.
// Denominator: partials t=lane+64g (R11 strided-512 chains), per-group shfl
// tree (v[i]+=v[i+off] pairing), final ((g0+g4)+(g2+g6))+((g1+g5)+(g3+g7)).
__global__ __launch_bounds__(256) void attn_v6_k(const float* __restrict__ qkv,
    const float* __restrict__ sink, float* __restrict__ y){
  __shared__ float arr[AQ][2049];       // 32.0KiB
  __shared__ float Ks[64][68];          // 17.0KiB (K chunks, then V chunks)
  const int tid = threadIdx.x;
  const int lane = tid & 63, wv = tid >> 6;
  const int h = blockIdx.y, q0 = blockIdx.x*AQ;
  const int qa_w = q0 + wv;
  const int qmax = q0 + AQ - 1;
  const float snk = sink[h];

  // zero-init arr (masked slots must be exact 0)
  #pragma unroll
  for (int qi=0;qi<AQ;qi++)
    for (int s=tid; s<2049; s+=256) arr[qi][s] = 0.0f;

  // preload Q row into regs (wave-uniform address)
  float qv[64];
  {
    const float* qr = qkv + (size_t)qa_w*3072 + h*64;
    #pragma unroll
    for (int c4=0;c4<16;c4++){
      float4 v = *(const float4*)&qr[4*c4];
      qv[4*c4]=v.x; qv[4*c4+1]=v.y; qv[4*c4+2]=v.z; qv[4*c4+3]=v.w;
    }
  }

  // ---- scores: K chunks of 64 rows staged to LDS ----
  float ml = -3.402823466e38f;
  for (int base=0; base<=qmax; base+=64){
    __syncthreads();
    #pragma unroll
    for (int it=0; it<4; ++it){
      int id = it*256 + tid;
      int r = id >> 4, c4 = id & 15;
      int kr = base + r;
      if (kr < TT)
        *(float4*)&Ks[r][4*c4] = *(const float4*)&qkv[(size_t)kr*3072 + 1024 + h*64 + 4*c4];
    }
    __syncthreads();
    int kv = base + lane;
    if (kv <= qa_w){
      float s = 0.0f;
      #pragma unroll
      for (int c4=0;c4<16;c4++){        // d-ascending FMA chain (R11 order)
        float4 kf = *(const float4*)&Ks[lane][4*c4];
        s = __builtin_fmaf(qv[4*c4  ], kf.x, s);
        s = __builtin_fmaf(qv[4*c4+1], kf.y, s);
        s = __builtin_fmaf(qv[4*c4+2], kf.z, s);
        s = __builtin_fmaf(qv[4*c4+3], kf.w, s);
      }
      s = __fmul_rn(s, 0.125f);
      arr[wv][1+kv] = s;
      ml = fmaxf(ml, s);
    }
  }
  __syncthreads();                       // scores visible block-wide (and wave-wide)

  // ---- wave max (order-free) + sink ----
  #pragma unroll
  for (int off=1; off<64; off<<=1) ml = fmaxf(ml, __shfl_xor(ml, off, 64));
  float m = fmaxf(ml, snk);

  // ---- exp (OCML expf) over own wave's slots; sink-exp in slot 0 ----
  for (int s=1+lane; s<=1+qa_w; s+=64)
    arr[wv][s] = expf(__fsub_rn(arr[wv][s], m));
  if (lane==0) arr[wv][0] = expf(__fsub_rn(snk, m));

  // ---- denominator, wave-local: partials t=lane+64g, R11 chain order ----
  float pg[8];
  #pragma unroll
  for (int g=0; g<8; ++g){
    int t = lane + 64*g;
    float a = 0.0f;
    for (int s=t; s<2049; s+=512) a = __fadd_rn(a, arr[wv][s]);
    pg[g] = a;
  }
  #pragma unroll
  for (int g=0; g<8; ++g){
    #pragma unroll
    for (int off=32; off; off>>=1)
      pg[g] = __fadd_rn(pg[g], __shfl_down(pg[g], off, 64));
  }
  float den;
  {
    // lane0 holds group sums; combine with the exact fin-tree pairing
    float t04 = __fadd_rn(pg[0], pg[4]);
    float t26 = __fadd_rn(pg[2], pg[6]);
    float t15 = __fadd_rn(pg[1], pg[5]);
    float t37 = __fadd_rn(pg[3], pg[7]);
    float d0 = __fadd_rn(__fadd_rn(t04, t26), __fadd_rn(t15, t37));
    den = __shfl(d0, 0, 64);
  }

  // ---- probs in place (own wave's slots) ----
  for (int s=1+lane; s<=1+qa_w; s+=64)
    arr[wv][s] = __fdiv_rn(arr[wv][s], den);

  // ---- PV: V chunks staged to LDS; kv-ascending single-acc chain ----
  float acc = 0.0f;
  for (int base=0; base<=qmax; base+=64){
    __syncthreads();                     // prev chunk consumed / probs ready
    #pragma unroll
    for (int it=0; it<4; ++it){
      int id = it*256 + tid;
      int r = id >> 4, c4 = id & 15;
      int kr = base + r;
      if (kr < TT)
        *(float4*)&Ks[r][4*c4] = *(const float4*)&qkv[(size_t)kr*3072 + 2048 + h*64 + 4*c4];
    }
    __syncthreads();
    int lim = qa_w - base; if (lim > 63) lim = 63;
    int j = 0;
    for (; j + 8 <= lim + 1; j += 8){
      #pragma unroll
      for (int e=0;e<8;e++)
        acc = __builtin_fmaf(arr[wv][1+base+j+e], Ks[j+e][lane], acc);
    }
    for (; j <= lim; ++j)
      acc = __builtin_fmaf(arr[wv][1+base+j], Ks[j][lane], acc);
  }
  y[(size_t)qa_w*DD + h*64 + lane] = acc;
}

// -------- abs top-k on f32 bits: exact radix select; zero in place --------
__global__ __launch_bounds__(256) void topk32_k(float* __restrict__ h,
    const int* __restrict__ kptr){
  const int row = blockIdx.x, tid = threadIdx.x;
  __shared__ int suf[256];
  __shared__ int s_sel, s_k;
  float* hr = h + (size_t)row*DMM;
  int kk = kptr[0];
  u32 prefix = 0u;
  for (int pass=0; pass<4; pass++){
    int shift = 24 - 8*pass;
    u32 hi_mask = pass ? (0xFFFFFFFFu << (shift+8)) : 0u;
    suf[tid] = 0;
    __syncthreads();
    for (int i=0;i<16;i++){
      u32 b = __float_as_uint(hr[tid + 256*i]) & 0x7fffffffu;
      if ((b & hi_mask) == prefix) atomicAdd(&suf[(b>>shift)&255], 1);
    }
    __syncthreads();
    for (int s=1;s<256;s<<=1){
      int v2 = (tid+s<256) ? suf[tid+s] : 0;
      __syncthreads();
      suf[tid] += v2;
      __syncthreads();
    }
    int nxt = (tid<255) ? suf[tid+1] : 0;
    if (suf[tid] >= kk && nxt < kk){ s_sel = tid; s_k = kk - nxt; }
    __syncthreads();
    prefix |= ((u32)s_sel) << shift;
    kk = s_k;
    __syncthreads();
  }
  for (int i=0;i<16;i++){
    int e = tid + 256*i;
    u32 b = __float_as_uint(hr[e]) & 0x7fffffffu;
    if (b < prefix) hr[e] = 0.0f;
  }
}

// ---------------- host launcher ----------------
extern "C" void kernel_launch(void* const* d_in, const int* in_sizes, int n_in,
                              void* d_out, int out_size, void* d_ws, size_t ws_size,
                              hipStream_t stream){
  const int*   idx  = (const int*)  d_in[0];
  const float* wte  = (const float*)d_in[1];
  const float* wpe  = (const float*)d_in[2];
  const float* ln1  = (const float*)d_in[3];
  const float* ln2  = (const float*)d_in[4];
  const float* Wa   = (const float*)d_in[5];
  const float* Wap  = (const float*)d_in[6];
  const float* Wf   = (const float*)d_in[7];
  const float* Wp   = (const float*)d_in[8];
  const float* sink = (const float*)d_in[9];
  const float* lnf  = (const float*)d_in[10];
  const float* lmw  = (const float*)d_in[11];
  const int*   kptr = (const int*)  d_in[12];
  (void)in_sizes; (void)n_in; (void)out_size; (void)ws_size;

  // ---- workspace: 80 MB, all fp32, no aliasing ----
  char* w = (char*)d_ws;
  float* x   = (float*)(w);                 // [0, 8M)
  float* xn  = (float*)(w + 8388608);       // [8M, 16M)
  float* qkv = (float*)(w + 16777216);      // [16M, 40M)
  float* y   = (float*)(w + 41943040);      // [40M, 48M)
  float* h   = (float*)(w + 50331648);      // [48M, 80M)

  embed32_k<<<TT, 256, 0, stream>>>(idx, wte, wpe, x);

  for (int l=0; l<4; l++){
    rms_xla_k<<<TT, 64, 0, stream>>>(x, ln1 + l*DD, xn);
    gemm_db_k<0,2><<<dim3(3072/128, TT/128), 256, 0, stream>>>(xn, Wa + (size_t)l*1024*3072, qkv, TT, 3072, 1024);
    attn_v6_k<<<dim3(TT/AQ, HH), 256, 0, stream>>>(qkv, sink + l*HH, y);
    gemm_db_k<1,1><<<dim3(1024/64, TT/128), 256, 0, stream>>>(y, Wap + (size_t)l*1024*1024, x, TT, 1024, 1024);
    rms_xla_k<<<TT, 64, 0, stream>>>(x, ln2 + l*DD, xn);
    gemm_db_k<2,2><<<dim3(4096/128, TT/128), 256, 0, stream>>>(xn, Wf + (size_t)l*1024*4096, h, TT, 4096, 1024);
    topk32_k<<<TT, 256, 0, stream>>>(h, kptr);
    gemm_db_k<1,1><<<dim3(1024/64, TT/128), 256, 0, stream>>>(h, Wp + (size_t)l*4096*1024, x, TT, 1024, 4096);
  }

  rms_xla_k<<<TT, 64, 0, stream>>>(x, lnf, xn);
  gemm_db_k<0,2><<<dim3(VV/128, TT/128), 256, 0, stream>>>(xn, lmw, (float*)d_out, TT, VV, 1024);
}